// Round 7
// baseline (34.600 us; speedup 1.0000x reference)
//
#include <hip/hip_runtime.h>

// Separable QP projection: hybrid bisection + Illinois false-position.
// One 256-thread block per row (B=4096, N=4096), 16 elems/thread.
//
// R6 post-mortem: VGPR_Count=48 proved the compiler was NOT keeping the
// 64 floats of per-element state in registers -- it rematerialized them
// from cache loads every iteration (per-sum cost 1.7us vs 0.64us ideal).
// Fix: __launch_bounds__(256, 4) -> VGPR budget 512/4 = 128, enough for
// za/ia/ma/Ma[16] + accumulators (~110). Algorithm unchanged from R6.

#define BISECT_STEPS 6
#define TOTAL_STEPS  9   // 6 bisection + 3 Illinois

// ---- DPP wave64 reduction helpers (gfx9-family row ops) ----
template<int CTRL, int RM>
__device__ __forceinline__ float dpp_add(float v) {
    int t = __builtin_amdgcn_update_dpp(0, __float_as_int(v), CTRL, RM, 0xf, false);
    return v + __int_as_float(t);
}
template<int CTRL, int RM>
__device__ __forceinline__ float dpp_min(float v) {
    int t = __builtin_amdgcn_update_dpp(0x7f800000, __float_as_int(v), CTRL, RM, 0xf, false);
    return fminf(v, __int_as_float(t));
}
template<int CTRL, int RM>
__device__ __forceinline__ float dpp_max(float v) {
    int t = __builtin_amdgcn_update_dpp(0xff800000, __float_as_int(v), CTRL, RM, 0xf, false);
    return fmaxf(v, __int_as_float(t));
}

__device__ __forceinline__ float wave_sum(float v) {
    v = dpp_add<0x111, 0xf>(v);   // row_shr:1
    v = dpp_add<0x112, 0xf>(v);   // row_shr:2
    v = dpp_add<0x114, 0xf>(v);   // row_shr:4
    v = dpp_add<0x118, 0xf>(v);   // row_shr:8
    v = dpp_add<0x142, 0xa>(v);   // row_bcast:15
    v = dpp_add<0x143, 0xc>(v);   // row_bcast:31
    return __int_as_float(__builtin_amdgcn_readlane(__float_as_int(v), 63));
}
__device__ __forceinline__ float wave_min(float v) {
    v = dpp_min<0x111, 0xf>(v);
    v = dpp_min<0x112, 0xf>(v);
    v = dpp_min<0x114, 0xf>(v);
    v = dpp_min<0x118, 0xf>(v);
    v = dpp_min<0x142, 0xa>(v);
    v = dpp_min<0x143, 0xc>(v);
    return __int_as_float(__builtin_amdgcn_readlane(__float_as_int(v), 63));
}
__device__ __forceinline__ float wave_max(float v) {
    v = dpp_max<0x111, 0xf>(v);
    v = dpp_max<0x112, 0xf>(v);
    v = dpp_max<0x114, 0xf>(v);
    v = dpp_max<0x118, 0xf>(v);
    v = dpp_max<0x142, 0xa>(v);
    v = dpp_max<0x143, 0xc>(v);
    return __int_as_float(__builtin_amdgcn_readlane(__float_as_int(v), 63));
}

__global__ __launch_bounds__(256, 4) void qp_proj_n4096(
    const float* __restrict__ z,
    const float* __restrict__ gamma,
    const float* __restrict__ mlo,
    const float* __restrict__ mhi,
    const float* __restrict__ xi,
    float* __restrict__ out)
{
    constexpr int N = 4096;
    const int row  = blockIdx.x;
    const int tid  = threadIdx.x;     // 0..255
    const int lane = tid & 63;
    const int wid  = tid >> 6;        // 0..3

    const float4* zrow = reinterpret_cast<const float4*>(z + (size_t)row * N);
    const float4* g4   = reinterpret_cast<const float4*>(gamma);
    const float4* m4   = reinterpret_cast<const float4*>(mlo);
    const float4* M4   = reinterpret_cast<const float4*>(mhi);
    float4*       orow = reinterpret_cast<float4*>(out + (size_t)row * N);

    // Per-thread element state; launch_bounds(256,4) gives the allocator
    // a 128-VGPR budget so these 64 floats stay register-resident.
    float za[16], ia[16], ma[16], Ma[16];

    float pmin =  INFINITY;   // partial min of 2g*(m - z)
    float pmax = -INFINITY;   // partial max of 2g*(M - z)
    float psm  = 0.0f;        // partial sum of m  (g(lo) = sum m - xi)
    float psM  = 0.0f;        // partial sum of M  (g(hi) = sum M - xi)

    #pragma unroll
    for (int k = 0; k < 4; ++k) {
        const int idx = tid + k * 256;           // float4 index, coalesced
        const float4 zz = zrow[idx];
        const float4 gg = g4[idx];
        const float4 mm = m4[idx];
        const float4 MM = M4[idx];

        const float zs[4] = {zz.x, zz.y, zz.z, zz.w};
        const float gs[4] = {gg.x, gg.y, gg.z, gg.w};
        const float ms[4] = {mm.x, mm.y, mm.z, mm.w};
        const float Ms[4] = {MM.x, MM.y, MM.z, MM.w};

        #pragma unroll
        for (int c = 0; c < 4; ++c) {
            const int j = 4 * k + c;
            const float tg = 2.0f * gs[c];
            za[j] = zs[c];
            ia[j] = 1.0f / tg;
            ma[j] = ms[c];
            Ma[j] = Ms[c];
            pmin = fminf(pmin, tg * (ms[c] - zs[c]));
            pmax = fmaxf(pmax, tg * (Ms[c] - zs[c]));
            psm += ms[c];
            psM += Ms[c];
        }
    }

    // ---- block reduce: bounds + endpoint g values (one barrier) ----
    __shared__ float wmin[4], wmax[4], wsm[4], wsM[4];
    __shared__ float wsum[2][4];      // double-buffered: one barrier per iter

    pmin = wave_min(pmin);
    pmax = wave_max(pmax);
    psm  = wave_sum(psm);
    psM  = wave_sum(psM);
    if (lane == 0) { wmin[wid] = pmin; wmax[wid] = pmax; wsm[wid] = psm; wsM[wid] = psM; }
    __syncthreads();
    float lo = fminf(fminf(wmin[0], wmin[1]), fminf(wmin[2], wmin[3]));
    float hi = fmaxf(fmaxf(wmax[0], wmax[1]), fmaxf(wmax[2], wmax[3]));

    const float xir = xi[row];
    float glo = (wsm[0] + wsm[1] + wsm[2] + wsm[3]) - xir;   // <= 0 at lo
    float ghi = (wsM[0] + wsM[1] + wsM[2] + wsM[3]) - xir;   // >= 0 at hi
    int side = 0;

    // ---- 6 bisection + 3 Illinois steps, each ONE sum ----
    for (int it = 0; it < TOTAL_STEPS; ++it) {
        const float w = hi - lo;
        float cand;
        if (it < BISECT_STEPS) {
            cand = fmaf(0.5f, w, lo);
        } else {
            const float denom = ghi - glo;           // > 0 (bracket invariant)
            cand = (lo * ghi - hi * glo) / denom;    // false-position point
            cand = fminf(fmaxf(cand, fmaf(0.0625f, w, lo)),
                         fmaf(-0.0625f, w, hi));     // strictly interior
        }

        // 4 accumulator chains (lower live-register peak than 16-wide tree)
        float t0 = 0.f, t1 = 0.f, t2 = 0.f, t3 = 0.f;
        #pragma unroll
        for (int q = 0; q < 4; ++q) {
            t0 += __builtin_amdgcn_fmed3f(fmaf(cand, ia[4*q+0], za[4*q+0]), ma[4*q+0], Ma[4*q+0]);
            t1 += __builtin_amdgcn_fmed3f(fmaf(cand, ia[4*q+1], za[4*q+1]), ma[4*q+1], Ma[4*q+1]);
            t2 += __builtin_amdgcn_fmed3f(fmaf(cand, ia[4*q+2], za[4*q+2]), ma[4*q+2], Ma[4*q+2]);
            t3 += __builtin_amdgcn_fmed3f(fmaf(cand, ia[4*q+3], za[4*q+3]), ma[4*q+3], Ma[4*q+3]);
        }
        const float sw = wave_sum((t0 + t1) + (t2 + t3));

        const int p = it & 1;
        if (lane == 0) wsum[p][wid] = sw;
        __syncthreads();
        // iter it's write to buf p is protected from iter it-2's reads by
        // the barrier at iter it-1 -> single barrier suffices.
        const float s = (wsum[p][0] + wsum[p][1] + wsum[p][2] + wsum[p][3]) - xir;

        if (s > 0.0f) {                 // root below cand
            hi = cand;
            if (side == 1) glo *= 0.5f; // Illinois stale-endpoint halving
            ghi = s;
            side = 1;
        } else {
            lo = cand;
            if (side == -1) ghi *= 0.5f;
            glo = s;
            side = -1;
        }
    }

    // final lambda: interpolated root of last bracket (piecewise-linear g),
    // clamped into [lo,hi]; midpoint fallback if degenerate.
    const float denom = ghi - glo;
    float lam = (denom > 0.0f) ? (lo * ghi - hi * glo) / denom
                               : fmaf(0.5f, hi - lo, lo);
    lam = fminf(fmaxf(lam, lo), hi);

    // ---- final x ----
    #pragma unroll
    for (int k = 0; k < 4; ++k) {
        const int idx = tid + k * 256;
        float4 r;
        float xs[4];
        #pragma unroll
        for (int c = 0; c < 4; ++c) {
            const int j = 4 * k + c;
            const float x = fmaf(lam, ia[j], za[j]);
            xs[c] = __builtin_amdgcn_fmed3f(x, ma[j], Ma[j]);
        }
        r.x = xs[0]; r.y = xs[1]; r.z = xs[2]; r.w = xs[3];
        orow[idx] = r;
    }
}

extern "C" void kernel_launch(void* const* d_in, const int* in_sizes, int n_in,
                              void* d_out, int out_size, void* d_ws, size_t ws_size,
                              hipStream_t stream) {
    const float* z     = (const float*)d_in[0];
    const float* gamma = (const float*)d_in[1];
    const float* m     = (const float*)d_in[2];
    const float* M     = (const float*)d_in[3];
    const float* xi    = (const float*)d_in[4];
    float* out = (float*)d_out;

    const int B = in_sizes[4];   // rows (xi has one entry per row)
    // Kernel is specialized to N == 4096 (16 elements / thread, 256 threads).
    qp_proj_n4096<<<dim3(B), dim3(256), 0, stream>>>(z, gamma, m, M, xi, out);
}